// Round 5
// baseline (7477.861 us; speedup 1.0000x reference)
//
#include <hip/hip_runtime.h>

typedef float f32x4 __attribute__((ext_vector_type(4)));
typedef __bf16 bf16x8 __attribute__((ext_vector_type(8)));
typedef unsigned short u16;

#define OUTC 4864
#define OUTT ((size_t)63 * OUTC)

__device__ __forceinline__ u16 f2bf(float f) {
    unsigned u = __float_as_uint(f);
    u += 0x7FFFu + ((u >> 16) & 1u);
    return (u16)(u >> 16);
}
__device__ __forceinline__ float bf2f(u16 h) { return __uint_as_float((unsigned)h << 16); }
__device__ __forceinline__ float fexp(float x) { return __expf(x); }
__device__ __forceinline__ float eluf(float x) { return x > 0.f ? x : fexp(x) - 1.f; }
__device__ __forceinline__ float splus(float x) { return x > 15.f ? x : __logf(1.f + fexp(x)); }
__device__ __forceinline__ float sigm(float x) { return 1.f / (1.f + fexp(-x)); }
__device__ __forceinline__ float tanhfast(float x) { return 2.f / (1.f + fexp(-2.f * x)) - 1.f; }
__device__ __forceinline__ int swz(int row, int cb) { return row * 128 + (cb ^ ((row & 7) << 4)); }
__device__ __forceinline__ int swzK(int row, int cb) { return row * 256 + (cb ^ ((row & 15) << 4)); }

// ======== BK=64 template (proven R3 path) — used by tail/obsc ========
template <int NT, class FA, class FE>
__device__ __forceinline__ void gemmN(char* As, FA fa, const u16* __restrict__ Bt,
                                      int ldb, int n0, int nstr, int K, int m0, FE fe) {
    char* Bs = As + 8192;
    const int tid = threadIdx.x;
    const int lane = tid & 63;
    const int w = tid >> 6;
    const int wr = (w >> 1) * 32, wc = (w & 1) * 32;
    f32x4 acc[NT][4];
    f32x4 zf = {0.f, 0.f, 0.f, 0.f};
#pragma unroll
    for (int j = 0; j < NT; j++)
#pragma unroll
        for (int q = 0; q < 4; q++) acc[j][q] = zf;
    const int r0 = tid >> 3;
    const int ke = (tid & 7) * 8;
    const int cb = (tid & 7) * 16;
    uint4 av0 = fa(m0 + r0, ke);
    uint4 av1 = fa(m0 + r0 + 32, ke);
    uint4 bv[NT][2];
#pragma unroll
    for (int j = 0; j < NT; j++) {
        bv[j][0] = *(const uint4*)(Bt + (size_t)(n0 + j * nstr + r0) * ldb + ke);
        bv[j][1] = *(const uint4*)(Bt + (size_t)(n0 + j * nstr + r0 + 32) * ldb + ke);
    }
    for (int k0 = 0; k0 < K; k0 += 64) {
        __syncthreads();
        *(uint4*)(As + swz(r0, cb)) = av0;
        *(uint4*)(As + swz(r0 + 32, cb)) = av1;
#pragma unroll
        for (int j = 0; j < NT; j++) {
            char* B = Bs + j * 8192;
            *(uint4*)(B + swz(r0, cb)) = bv[j][0];
            *(uint4*)(B + swz(r0 + 32, cb)) = bv[j][1];
        }
        __syncthreads();
        if (k0 + 64 < K) {
            int k1 = k0 + 64 + ke;
            av0 = fa(m0 + r0, k1);
            av1 = fa(m0 + r0 + 32, k1);
#pragma unroll
            for (int j = 0; j < NT; j++) {
                bv[j][0] = *(const uint4*)(Bt + (size_t)(n0 + j * nstr + r0) * ldb + k1);
                bv[j][1] = *(const uint4*)(Bt + (size_t)(n0 + j * nstr + r0 + 32) * ldb + k1);
            }
        }
#pragma unroll
        for (int kk = 0; kk < 64; kk += 32) {
            const int fcb = kk * 2 + (lane >> 4) * 16;
            bf16x8 a0 = *(const bf16x8*)(As + swz(wr + (lane & 15), fcb));
            bf16x8 a1 = *(const bf16x8*)(As + swz(wr + 16 + (lane & 15), fcb));
#pragma unroll
            for (int j = 0; j < NT; j++) {
                char* B = Bs + j * 8192;
                bf16x8 b0 = *(const bf16x8*)(B + swz(wc + (lane & 15), fcb));
                bf16x8 b1 = *(const bf16x8*)(B + swz(wc + 16 + (lane & 15), fcb));
                acc[j][0] = __builtin_amdgcn_mfma_f32_16x16x32_bf16(a0, b0, acc[j][0], 0, 0, 0);
                acc[j][1] = __builtin_amdgcn_mfma_f32_16x16x32_bf16(a0, b1, acc[j][1], 0, 0, 0);
                acc[j][2] = __builtin_amdgcn_mfma_f32_16x16x32_bf16(a1, b0, acc[j][2], 0, 0, 0);
                acc[j][3] = __builtin_amdgcn_mfma_f32_16x16x32_bf16(a1, b1, acc[j][3], 0, 0, 0);
            }
        }
    }
    const int er = (lane >> 4) * 4, ec = lane & 15;
#pragma unroll
    for (int q = 0; q < 4; q++) {
        int rr = m0 + wr + (q >> 1) * 16 + er;
        int cc = n0 + wc + (q & 1) * 16 + ec;
#pragma unroll
        for (int r = 0; r < 4; r++) {
            float vals[NT];
#pragma unroll
            for (int j = 0; j < NT; j++) vals[j] = acc[j][q][r];
            fe(rr + r, cc, vals);
        }
    }
}

// ======== BK=128 template — chain kernels (fewer latency-bound iterations) ========
// requires K % 128 == 0
template <int NT, class FA, class FE>
__device__ __forceinline__ void gemmK(char* As, FA fa, const u16* __restrict__ Bt,
                                      int ldb, int n0, int nstr, int K, int m0, FE fe) {
    char* Bs = As + 16384;
    const int tid = threadIdx.x;
    const int lane = tid & 63;
    const int w = tid >> 6;
    const int wr = (w >> 1) * 32, wc = (w & 1) * 32;
    f32x4 acc[NT][4];
    f32x4 zf = {0.f, 0.f, 0.f, 0.f};
#pragma unroll
    for (int j = 0; j < NT; j++)
#pragma unroll
        for (int q = 0; q < 4; q++) acc[j][q] = zf;
    const int ar = tid >> 2;          // 0..63
    const int ace = (tid & 3) * 32;   // element offset within 128
    const int acb = (tid & 3) * 64;   // byte offset within 256
    uint4 av[4], bv[NT][4];
#pragma unroll
    for (int j = 0; j < 4; j++) av[j] = fa(m0 + ar, ace + j * 8);
#pragma unroll
    for (int n = 0; n < NT; n++)
#pragma unroll
        for (int j = 0; j < 4; j++)
            bv[n][j] = *(const uint4*)(Bt + (size_t)(n0 + n * nstr + ar) * ldb + ace + j * 8);
    for (int k0 = 0; k0 < K; k0 += 128) {
        __syncthreads();
#pragma unroll
        for (int j = 0; j < 4; j++) *(uint4*)(As + swzK(ar, acb + j * 16)) = av[j];
#pragma unroll
        for (int n = 0; n < NT; n++) {
            char* B = Bs + n * 16384;
#pragma unroll
            for (int j = 0; j < 4; j++) *(uint4*)(B + swzK(ar, acb + j * 16)) = bv[n][j];
        }
        __syncthreads();
        if (k0 + 128 < K) {
            int k1 = k0 + 128 + ace;
#pragma unroll
            for (int j = 0; j < 4; j++) av[j] = fa(m0 + ar, k1 + j * 8);
#pragma unroll
            for (int n = 0; n < NT; n++)
#pragma unroll
                for (int j = 0; j < 4; j++)
                    bv[n][j] = *(const uint4*)(Bt + (size_t)(n0 + n * nstr + ar) * ldb + k1 + j * 8);
        }
#pragma unroll
        for (int kk = 0; kk < 128; kk += 32) {
            const int fcb = kk * 2 + (lane >> 4) * 16;
            bf16x8 a0 = *(const bf16x8*)(As + swzK(wr + (lane & 15), fcb));
            bf16x8 a1 = *(const bf16x8*)(As + swzK(wr + 16 + (lane & 15), fcb));
#pragma unroll
            for (int n = 0; n < NT; n++) {
                char* B = Bs + n * 16384;
                bf16x8 b0 = *(const bf16x8*)(B + swzK(wc + (lane & 15), fcb));
                bf16x8 b1 = *(const bf16x8*)(B + swzK(wc + 16 + (lane & 15), fcb));
                acc[n][0] = __builtin_amdgcn_mfma_f32_16x16x32_bf16(a0, b0, acc[n][0], 0, 0, 0);
                acc[n][1] = __builtin_amdgcn_mfma_f32_16x16x32_bf16(a0, b1, acc[n][1], 0, 0, 0);
                acc[n][2] = __builtin_amdgcn_mfma_f32_16x16x32_bf16(a1, b0, acc[n][2], 0, 0, 0);
                acc[n][3] = __builtin_amdgcn_mfma_f32_16x16x32_bf16(a1, b1, acc[n][3], 0, 0, 0);
            }
        }
    }
    const int er = (lane >> 4) * 4, ec = lane & 15;
#pragma unroll
    for (int q = 0; q < 4; q++) {
        int rr = m0 + wr + (q >> 1) * 16 + er;
        int cc = n0 + wc + (q & 1) * 16 + ec;
#pragma unroll
        for (int r = 0; r < 4; r++) {
            float vals[NT];
#pragma unroll
            for (int j = 0; j < NT; j++) vals[j] = acc[j][q][r];
            fe(rr + r, cc, vals);
        }
    }
}

// -------- prolog: all weight prep + init, one kernel --------
#define PREP_BLOCKS 2048
#define PGSTR (PREP_BLOCKS * 256)
__device__ __forceinline__ void tpose(const float* __restrict__ in, u16* __restrict__ out,
                                      int R, int C, int Rpad, int total, int gtid) {
    for (int i = gtid; i < total; i += PGSTR) {
        int r = i % Rpad;
        int bc = i / Rpad;
        int c = bc % C;
        int bb = bc / C;
        out[i] = (r < R) ? f2bf(in[((size_t)bb * R + r) * C + c]) : (u16)0;
    }
}
__device__ __forceinline__ void castb(const float* __restrict__ in, u16* __restrict__ out,
                                      int total, int gtid) {
    for (int i = gtid; i < total; i += PGSTR) out[i] = f2bf(in[i]);
}

__global__ void __launch_bounds__(256) k_prep(
    const float* W_embed, const float* W_ih, const float* W_hh, const float* W_ens,
    const float* Wp1, const float* Wp2, const float* Wq1, const float* Wq2,
    u16* Wembed_t, u16* Wih_b, u16* Whh_b, u16* Wens_t,
    u16* Wp1_t, u16* Wp2_t, u16* Wq1d_t, u16* Wq1o_t, u16* Wq2_t,
    const float* init_deter, const float* init_stoch, const float* action,
    const float* nonterms, float* deter, u16* h_nt, u16* x_embed) {
    int gtid = blockIdx.x * 256 + threadIdx.x;
    tpose(W_embed, Wembed_t, 288, 1024, 384, 1024 * 384, gtid);
    castb(W_ih, Wih_b, 3072 * 1024, gtid);
    castb(W_hh, Whh_b, 3072 * 1024, gtid);
    tpose(W_ens, Wens_t, 1024, 256, 1024, 5 * 256 * 1024, gtid);
    tpose(Wp1, Wp1_t, 1024, 1024, 1024, 1024 * 1024, gtid);
    tpose(Wp2, Wp2_t, 1024, 512, 1024, 512 * 1024, gtid);
    tpose(Wq1, Wq1d_t, 1024, 1024, 1024, 1024 * 1024, gtid);
    tpose(Wq1 + 1024 * 1024, Wq1o_t, 1024, 1024, 1024, 1024 * 1024, gtid);
    tpose(Wq2, Wq2_t, 1024, 512, 1024, 512 * 1024, gtid);
    for (int idx = gtid; idx < 262144; idx += PGSTR) {
        int b = idx >> 10, d = idx & 1023;
        float nt0 = nonterms[b * 64];
        float dv = init_deter[idx];
        deter[idx] = dv;
        h_nt[idx] = f2bf(dv * nt0);
        if (d < 256) {
            x_embed[b * 384 + d] = f2bf(init_stoch[b * 256 + d] * nt0);
        } else if (d < 384) {
            int c = d - 256;
            x_embed[b * 384 + d] = (c < 32) ? f2bf(action[(size_t)b * 2048 + c] * nt0) : (u16)0;
        }
    }
}

// -------- OBSC precompute (1008 blocks, BK=64 NT=4 proven path) --------
__global__ void __launch_bounds__(256) k_obsc(const float* __restrict__ obs,
                                              const u16* __restrict__ Wq1o_t,
                                              u16* __restrict__ OBSC) {
    __shared__ char sm[40960];
    int bid = blockIdx.x;
    int rb = bid >> 2, cg = bid & 3;
    int m0 = rb * 64, n0 = cg * 256;
    auto fa = [&](int r, int k) {
        int tt = r >> 8, bb = r & 255;
        const float* p = obs + ((size_t)bb * 64 + tt) * 1024 + k;
        float4 f0 = *(const float4*)p, f1 = *(const float4*)(p + 4);
        union { u16 h[8]; uint4 q; } x;
        x.h[0] = f2bf(f0.x); x.h[1] = f2bf(f0.y); x.h[2] = f2bf(f0.z); x.h[3] = f2bf(f0.w);
        x.h[4] = f2bf(f1.x); x.h[5] = f2bf(f1.y); x.h[6] = f2bf(f1.z); x.h[7] = f2bf(f1.w);
        return x.q;
    };
    auto fe = [&](int r, int n, const float* v) {
#pragma unroll
        for (int j = 0; j < 4; j++) OBSC[(size_t)r * 1024 + n + j * 64] = f2bf(v[j]);
    };
    gemmN<4>(sm, fa, Wq1o_t, 1024, n0, 64, 1024, m0, fe);
}

// -------- S1: sa (64 blocks) || gh(t) (192 blocks) --------
__global__ void __launch_bounds__(256) k_sa_gh(const u16* __restrict__ xe,
                                               const u16* __restrict__ Wembed_t,
                                               const float* __restrict__ b_embed,
                                               u16* __restrict__ sa,
                                               const u16* __restrict__ h_nt,
                                               const u16* __restrict__ Whh_b,
                                               const float* __restrict__ b_hh,
                                               float* __restrict__ gh) {
    __shared__ char sm[32768];
    int bid = blockIdx.x;
    if (bid < 64) {
        int m0 = (bid >> 4) * 64, n0 = (bid & 15) * 64;
        auto fa = [&](int r, int k) { return *(const uint4*)(xe + r * 384 + k); };
        auto fe = [&](int r, int n, const float* v) {
            sa[r * 1024 + n] = f2bf(eluf(v[0] + b_embed[n]));
        };
        gemmK<1>(sm, fa, Wembed_t, 384, n0, 0, 384, m0, fe);
    } else {
        int j = bid - 64;
        int m0 = (j / 48) * 64, n0 = (j % 48) * 64;
        auto fa = [&](int r, int k) { return *(const uint4*)(h_nt + r * 1024 + k); };
        auto fe = [&](int r, int n, const float* v) { gh[(size_t)r * 3072 + n] = v[0] + b_hh[n]; };
        gemmK<1>(sm, fa, Whh_b, 1024, n0, 0, 1024, m0, fe);
    }
}

// -------- S2: gi GEMM (NT=3 over gates) + fused GRU epilogue (64 blocks) --------
__global__ void __launch_bounds__(256) k_gi_gru(const u16* __restrict__ sa,
                                                const u16* __restrict__ Wih_b,
                                                const float* __restrict__ b_ih,
                                                const float* __restrict__ gh,
                                                const float* __restrict__ nonterms,
                                                float* __restrict__ deter,
                                                u16* __restrict__ deter_hist,
                                                u16* __restrict__ h_nt,
                                                float* __restrict__ out, int t) {
    __shared__ char sm[65536];
    int m0 = blockIdx.y * 64, n0 = blockIdx.x * 64;   // n0 = d-tile
    auto fa = [&](int r, int k) { return *(const uint4*)(sa + r * 1024 + k); };
    auto fe = [&](int r, int d, const float* v) {
        size_t gb = (size_t)r * 3072;
        float rg = sigm(v[0] + b_ih[d] + gh[gb + d]);
        float zg = sigm(v[1] + b_ih[1024 + d] + gh[gb + 1024 + d]);
        float ng = tanhfast(v[2] + b_ih[2048 + d] + rg * gh[gb + 2048 + d]);
        float h = deter[r * 1024 + d] * nonterms[r * 64 + t];
        float dn = (1.f - zg) * ng + zg * h;
        deter[r * 1024 + d] = dn;
        deter_hist[(size_t)t * 262144 + r * 1024 + d] = f2bf(dn);
        h_nt[r * 1024 + d] = f2bf(dn * nonterms[r * 64 + t + 1]);
        float* ob = out + (size_t)r * OUTT + (size_t)t * OUTC;
        ob[768 + d] = dn;
        ob[2560 + d] = dn;
    };
    gemmK<3>(sm, fa, Wih_b, 1024, n0, 1024, 1024, m0, fe);
}

// -------- S3: HQ = elu(deter@Wq1d + OBSC + bq1) (64 blocks) --------
__global__ void __launch_bounds__(256) k_hq(const u16* __restrict__ deter_hist,
                                            const u16* __restrict__ Wq1d_t,
                                            const float* __restrict__ bq1,
                                            const u16* __restrict__ OBSC,
                                            u16* __restrict__ HQ, int t) {
    __shared__ char sm[32768];
    int m0 = blockIdx.y * 64, n0 = blockIdx.x * 64;
    const u16* A = deter_hist + (size_t)t * 262144;
    const u16* ob = OBSC + (size_t)t * 262144;
    auto fa = [&](int r, int k) { return *(const uint4*)(A + r * 1024 + k); };
    auto fe = [&](int r, int n, const float* v) {
        HQ[r * 1024 + n] = f2bf(eluf(v[0] + bq1[n] + bf2f(ob[r * 1024 + n])));
    };
    gemmK<1>(sm, fa, Wq1d_t, 1024, n0, 0, 1024, m0, fe);
}

// -------- S4: q2 + post sampling + x_embed (20 blocks) --------
__global__ void __launch_bounds__(256) k_q2dist(const u16* __restrict__ HQ,
                                                const u16* __restrict__ Wq2_t,
                                                const float* __restrict__ bq2,
                                                const float* __restrict__ noise_q,
                                                const float* __restrict__ nonterms,
                                                const float* __restrict__ action,
                                                float* __restrict__ out,
                                                u16* __restrict__ x_embed, int t) {
    __shared__ char sm[49152];
    int bid = blockIdx.x;
    if (bid < 16) {
        int m0 = (bid >> 2) * 64, n0 = (bid & 3) * 64;
        auto fa = [&](int r, int k) { return *(const uint4*)(HQ + r * 1024 + k); };
        auto fe = [&](int r, int s, const float* v) {
            float m = v[0] + bq2[s];
            float sd = splus(v[1] + bq2[s + 256]) + 0.1f;
            float eps = noise_q[(size_t)t * 65536 + r * 256 + s];
            float st = m + sd * eps;
            float* obp = out + (size_t)r * OUTT + (size_t)t * OUTC + 1792;
            obp[s] = m;
            obp[256 + s] = sd;
            obp[512 + s] = st;
            float ntn = nonterms[r * 64 + t + 1];
            x_embed[r * 384 + s] = f2bf(st * ntn);
        };
        gemmK<2>(sm, fa, Wq2_t, 1024, n0, 256, 1024, m0, fe);
    } else {
        for (int i = (bid - 16) * 256 + threadIdx.x; i < 32768; i += 1024) {
            int b = i >> 7, c = i & 127;   // cols 256..383
            float ntn = nonterms[b * 64 + t + 1];
            u16 v = 0;
            if (c < 32) v = f2bf(action[(size_t)b * 2048 + (size_t)(t + 1) * 32 + c] * ntn);
            x_embed[b * 384 + 256 + c] = v;
        }
    }
}

// -------- batched epilogues (M = 16128, BK=64 proven path) --------
__global__ void __launch_bounds__(256) k_ens(const u16* __restrict__ sa_hist,
                                             const u16* __restrict__ Wens_t,
                                             const float* __restrict__ b_ens,
                                             float* __restrict__ out) {
    __shared__ char sm[40960];
    int m0 = blockIdx.y * 64, n0 = blockIdx.x * 256;
    auto fa = [&](int r, int k) { return *(const uint4*)(sa_hist + (size_t)r * 1024 + k); };
    auto fe = [&](int r, int cc, const float* v) {
        int tt = r >> 8, b = r & 255;
        float* op = out + (size_t)b * OUTT + (size_t)tt * OUTC + 3584;
#pragma unroll
        for (int j = 0; j < 4; j++) {
            int n = cc + j * 64;
            op[n] = v[j] + b_ens[n];
        }
    };
    gemmN<4>(sm, fa, Wens_t, 1024, n0, 64, 1024, m0, fe);
}

__global__ void __launch_bounds__(256) k_hp(const u16* __restrict__ deter_hist,
                                            const u16* __restrict__ Wp1_t,
                                            const float* __restrict__ bp1,
                                            u16* __restrict__ HP) {
    __shared__ char sm[40960];
    int m0 = blockIdx.y * 64, n0 = blockIdx.x * 256;
    auto fa = [&](int r, int k) { return *(const uint4*)(deter_hist + (size_t)r * 1024 + k); };
    auto fe = [&](int r, int cc, const float* v) {
#pragma unroll
        for (int j = 0; j < 4; j++) {
            int n = cc + j * 64;
            HP[(size_t)r * 1024 + n] = f2bf(eluf(v[j] + bp1[n]));
        }
    };
    gemmN<4>(sm, fa, Wp1_t, 1024, n0, 64, 1024, m0, fe);
}

__global__ void __launch_bounds__(256) k_p2(const u16* __restrict__ HP,
                                            const u16* __restrict__ Wp2_t,
                                            const float* __restrict__ bp2,
                                            const float* __restrict__ noise_p,
                                            float* __restrict__ out) {
    __shared__ char sm[24576];
    int m0 = blockIdx.y * 64, n0 = blockIdx.x * 64;
    auto fa = [&](int r, int k) { return *(const uint4*)(HP + (size_t)r * 1024 + k); };
    auto fe = [&](int r, int s, const float* v) {
        int tt = r >> 8, b = r & 255;
        float m = v[0] + bp2[s];
        float sd = splus(v[1] + bp2[s + 256]) + 0.1f;
        float eps = noise_p[(size_t)tt * 65536 + b * 256 + s];
        float st = m + sd * eps;
        float* obp = out + (size_t)b * OUTT + (size_t)tt * OUTC;
        obp[s] = m;
        obp[256 + s] = sd;
        obp[512 + s] = st;
    };
    gemmN<2>(sm, fa, Wp2_t, 1024, n0, 256, 1024, m0, fe);
}

// ---------------- host ----------------
extern "C" void kernel_launch(void* const* d_in, const int* in_sizes, int n_in,
                              void* d_out, int out_size, void* d_ws, size_t ws_size,
                              hipStream_t stream) {
    const float* obs = (const float*)d_in[1];
    const float* action = (const float*)d_in[2];
    const float* nonterms = (const float*)d_in[3];
    const float* init_deter = (const float*)d_in[4];
    const float* init_stoch = (const float*)d_in[5];
    const float* noise_p = (const float*)d_in[6];
    const float* noise_q = (const float*)d_in[7];
    const float* W_embed = (const float*)d_in[8];
    const float* b_embed = (const float*)d_in[9];
    const float* W_ens = (const float*)d_in[10];
    const float* b_ens = (const float*)d_in[11];
    const float* W_ih = (const float*)d_in[12];
    const float* W_hh = (const float*)d_in[13];
    const float* b_ih = (const float*)d_in[14];
    const float* b_hh = (const float*)d_in[15];
    const float* Wp1 = (const float*)d_in[16];
    const float* bp1 = (const float*)d_in[17];
    const float* Wp2 = (const float*)d_in[18];
    const float* bp2 = (const float*)d_in[19];
    const float* Wq1 = (const float*)d_in[20];
    const float* bq1 = (const float*)d_in[21];
    const float* Wq2 = (const float*)d_in[22];
    const float* bq2 = (const float*)d_in[23];
    float* out = (float*)d_out;

    char* ws = (char*)d_ws;
    size_t off = 0;
    auto alloc = [&](size_t bytes) {
        void* p = ws + off;
        off += (bytes + 255) & ~(size_t)255;
        return p;
    };
    u16* Wembed_t = (u16*)alloc((size_t)1024 * 384 * 2);
    u16* Wih_b = (u16*)alloc((size_t)3072 * 1024 * 2);
    u16* Whh_b = (u16*)alloc((size_t)3072 * 1024 * 2);
    u16* Wens_t = (u16*)alloc((size_t)1280 * 1024 * 2);
    u16* Wp1_t = (u16*)alloc((size_t)1024 * 1024 * 2);
    u16* Wp2_t = (u16*)alloc((size_t)512 * 1024 * 2);
    u16* Wq1d_t = (u16*)alloc((size_t)1024 * 1024 * 2);
    u16* Wq1o_t = (u16*)alloc((size_t)1024 * 1024 * 2);
    u16* Wq2_t = (u16*)alloc((size_t)512 * 1024 * 2);
    u16* OBSC = (u16*)alloc((size_t)16128 * 1024 * 2);  // reused as HP in epilogue
    u16* sa_hist = (u16*)alloc((size_t)16128 * 1024 * 2);
    u16* deter_hist = (u16*)alloc((size_t)16128 * 1024 * 2);
    u16* x_embed = (u16*)alloc((size_t)256 * 384 * 2);
    u16* h_nt = (u16*)alloc((size_t)256 * 1024 * 2);
    u16* HQ = (u16*)alloc((size_t)256 * 1024 * 2);
    float* deter = (float*)alloc((size_t)256 * 1024 * 4);
    float* gh = (float*)alloc((size_t)256 * 3072 * 4);
    (void)ws_size; (void)in_sizes; (void)n_in; (void)out_size;

    k_prep<<<PREP_BLOCKS, 256, 0, stream>>>(
        W_embed, W_ih, W_hh, W_ens, Wp1, Wp2, Wq1, Wq2,
        Wembed_t, Wih_b, Whh_b, Wens_t, Wp1_t, Wp2_t, Wq1d_t, Wq1o_t, Wq2_t,
        init_deter, init_stoch, action, nonterms, deter, h_nt, x_embed);
    k_obsc<<<1008, 256, 0, stream>>>(obs, Wq1o_t, OBSC);

    for (int t = 0; t < 63; t++) {
        u16* sa_t = sa_hist + (size_t)t * 262144;
        k_sa_gh<<<256, 256, 0, stream>>>(x_embed, Wembed_t, b_embed, sa_t,
                                         h_nt, Whh_b, b_hh, gh);
        k_gi_gru<<<dim3(16, 4), 256, 0, stream>>>(sa_t, Wih_b, b_ih, gh, nonterms,
                                                  deter, deter_hist, h_nt, out, t);
        k_hq<<<dim3(16, 4), 256, 0, stream>>>(deter_hist, Wq1d_t, bq1, OBSC, HQ, t);
        k_q2dist<<<24, 256, 0, stream>>>(HQ, Wq2_t, bq2, noise_q, nonterms, action,
                                         out, x_embed, t);
    }

    k_ens<<<dim3(5, 252), 256, 0, stream>>>(sa_hist, Wens_t, b_ens, out);
    u16* HP = OBSC;  // reuse
    k_hp<<<dim3(4, 252), 256, 0, stream>>>(deter_hist, Wp1_t, bp1, HP);
    k_p2<<<dim3(4, 252), 256, 0, stream>>>(HP, Wp2_t, bp2, noise_p, out);
}

// Round 6
// 5850.186 us; speedup vs baseline: 1.2782x; 1.2782x over previous
//
#include <hip/hip_runtime.h>

typedef float f32x4 __attribute__((ext_vector_type(4)));
typedef __bf16 bf16x8 __attribute__((ext_vector_type(8)));
typedef unsigned short u16;

#define OUTC 4864
#define OUTT ((size_t)63 * OUTC)

__device__ __forceinline__ u16 f2bf(float f) {
    unsigned u = __float_as_uint(f);
    u += 0x7FFFu + ((u >> 16) & 1u);
    return (u16)(u >> 16);
}
__device__ __forceinline__ float bf2f(u16 h) { return __uint_as_float((unsigned)h << 16); }
__device__ __forceinline__ float fexp(float x) { return __expf(x); }
__device__ __forceinline__ float eluf(float x) { return x > 0.f ? x : fexp(x) - 1.f; }
__device__ __forceinline__ float splus(float x) { return x > 15.f ? x : __logf(1.f + fexp(x)); }
__device__ __forceinline__ float sigm(float x) { return 1.f / (1.f + fexp(-x)); }
__device__ __forceinline__ float tanhfast(float x) { return 2.f / (1.f + fexp(-2.f * x)) - 1.f; }
__device__ __forceinline__ int swz(int row, int cb) { return row * 128 + (cb ^ ((row & 7) << 4)); }

// ======== 256-thread BK=64 depth-1 template (proven R1/R3 path) ========
template <int NT, class FA, class FE>
__device__ __forceinline__ void gemmN(char* As, FA fa, const u16* __restrict__ Bt,
                                      int ldb, int n0, int nstr, int K, int m0, FE fe) {
    char* Bs = As + 8192;
    const int tid = threadIdx.x;
    const int lane = tid & 63;
    const int w = tid >> 6;
    const int wr = (w >> 1) * 32, wc = (w & 1) * 32;
    f32x4 acc[NT][4];
    f32x4 zf = {0.f, 0.f, 0.f, 0.f};
#pragma unroll
    for (int j = 0; j < NT; j++)
#pragma unroll
        for (int q = 0; q < 4; q++) acc[j][q] = zf;
    const int r0 = tid >> 3;
    const int ke = (tid & 7) * 8;
    const int cb = (tid & 7) * 16;
    uint4 av0 = fa(m0 + r0, ke);
    uint4 av1 = fa(m0 + r0 + 32, ke);
    uint4 bv[NT][2];
#pragma unroll
    for (int j = 0; j < NT; j++) {
        bv[j][0] = *(const uint4*)(Bt + (size_t)(n0 + j * nstr + r0) * ldb + ke);
        bv[j][1] = *(const uint4*)(Bt + (size_t)(n0 + j * nstr + r0 + 32) * ldb + ke);
    }
    for (int k0 = 0; k0 < K; k0 += 64) {
        __syncthreads();
        *(uint4*)(As + swz(r0, cb)) = av0;
        *(uint4*)(As + swz(r0 + 32, cb)) = av1;
#pragma unroll
        for (int j = 0; j < NT; j++) {
            char* B = Bs + j * 8192;
            *(uint4*)(B + swz(r0, cb)) = bv[j][0];
            *(uint4*)(B + swz(r0 + 32, cb)) = bv[j][1];
        }
        __syncthreads();
        if (k0 + 64 < K) {
            int k1 = k0 + 64 + ke;
            av0 = fa(m0 + r0, k1);
            av1 = fa(m0 + r0 + 32, k1);
#pragma unroll
            for (int j = 0; j < NT; j++) {
                bv[j][0] = *(const uint4*)(Bt + (size_t)(n0 + j * nstr + r0) * ldb + k1);
                bv[j][1] = *(const uint4*)(Bt + (size_t)(n0 + j * nstr + r0 + 32) * ldb + k1);
            }
        }
#pragma unroll
        for (int kk = 0; kk < 64; kk += 32) {
            const int fcb = kk * 2 + (lane >> 4) * 16;
            bf16x8 a0 = *(const bf16x8*)(As + swz(wr + (lane & 15), fcb));
            bf16x8 a1 = *(const bf16x8*)(As + swz(wr + 16 + (lane & 15), fcb));
#pragma unroll
            for (int j = 0; j < NT; j++) {
                char* B = Bs + j * 8192;
                bf16x8 b0 = *(const bf16x8*)(B + swz(wc + (lane & 15), fcb));
                bf16x8 b1 = *(const bf16x8*)(B + swz(wc + 16 + (lane & 15), fcb));
                acc[j][0] = __builtin_amdgcn_mfma_f32_16x16x32_bf16(a0, b0, acc[j][0], 0, 0, 0);
                acc[j][1] = __builtin_amdgcn_mfma_f32_16x16x32_bf16(a0, b1, acc[j][1], 0, 0, 0);
                acc[j][2] = __builtin_amdgcn_mfma_f32_16x16x32_bf16(a1, b0, acc[j][2], 0, 0, 0);
                acc[j][3] = __builtin_amdgcn_mfma_f32_16x16x32_bf16(a1, b1, acc[j][3], 0, 0, 0);
            }
        }
    }
    const int er = (lane >> 4) * 4, ec = lane & 15;
#pragma unroll
    for (int q = 0; q < 4; q++) {
        int rr = m0 + wr + (q >> 1) * 16 + er;
        int cc = n0 + wc + (q & 1) * 16 + ec;
#pragma unroll
        for (int r = 0; r < 4; r++) {
            float vals[NT];
#pragma unroll
            for (int j = 0; j < NT; j++) vals[j] = acc[j][q][r];
            fe(rr + r, cc, vals);
        }
    }
}

// ======== 512-thread split-K(2) BK=64 depth-1 template — chain kernels ========
// Two 4-wave k-groups each do K/2 into private LDS; fp32 LDS reduce; kg0 runs fe.
// K must be even multiple of 128. LDS need: max(2*(1+NT)*8192, NT*16384) bytes.
template <int NT, class FA, class FE>
__device__ __forceinline__ void gemmS(char* sm, FA fa, const u16* __restrict__ Bt,
                                      int ldb, int n0, int nstr, int K, int m0, FE fe) {
    const int tid = threadIdx.x;          // 0..511
    const int lane = tid & 63;
    const int w = tid >> 6;               // 0..7
    const int kg = w >> 2;                // k-group 0/1
    const int wi = w & 3;                 // quadrant
    const int wr = (wi >> 1) * 32, wc = (wi & 1) * 32;
    const int Kh = K >> 1;
    const int kbase = kg * Kh;
    char* As = sm + kg * (1 + NT) * 8192;
    char* Bs = As + 8192;
    f32x4 acc[NT][4];
    f32x4 zf = {0.f, 0.f, 0.f, 0.f};
#pragma unroll
    for (int j = 0; j < NT; j++)
#pragma unroll
        for (int q = 0; q < 4; q++) acc[j][q] = zf;
    const int t2 = tid & 255;
    const int r0 = t2 >> 3;
    const int ke = (t2 & 7) * 8;
    const int cb = (t2 & 7) * 16;
    uint4 av0 = fa(m0 + r0, kbase + ke);
    uint4 av1 = fa(m0 + r0 + 32, kbase + ke);
    uint4 bv[NT][2];
#pragma unroll
    for (int j = 0; j < NT; j++) {
        bv[j][0] = *(const uint4*)(Bt + (size_t)(n0 + j * nstr + r0) * ldb + kbase + ke);
        bv[j][1] = *(const uint4*)(Bt + (size_t)(n0 + j * nstr + r0 + 32) * ldb + kbase + ke);
    }
    for (int k0 = 0; k0 < Kh; k0 += 64) {
        __syncthreads();
        *(uint4*)(As + swz(r0, cb)) = av0;
        *(uint4*)(As + swz(r0 + 32, cb)) = av1;
#pragma unroll
        for (int j = 0; j < NT; j++) {
            char* B = Bs + j * 8192;
            *(uint4*)(B + swz(r0, cb)) = bv[j][0];
            *(uint4*)(B + swz(r0 + 32, cb)) = bv[j][1];
        }
        __syncthreads();
        if (k0 + 64 < Kh) {
            int k1 = kbase + k0 + 64 + ke;
            av0 = fa(m0 + r0, k1);
            av1 = fa(m0 + r0 + 32, k1);
#pragma unroll
            for (int j = 0; j < NT; j++) {
                bv[j][0] = *(const uint4*)(Bt + (size_t)(n0 + j * nstr + r0) * ldb + k1);
                bv[j][1] = *(const uint4*)(Bt + (size_t)(n0 + j * nstr + r0 + 32) * ldb + k1);
            }
        }
#pragma unroll
        for (int kk = 0; kk < 64; kk += 32) {
            const int fcb = kk * 2 + (lane >> 4) * 16;
            bf16x8 a0 = *(const bf16x8*)(As + swz(wr + (lane & 15), fcb));
            bf16x8 a1 = *(const bf16x8*)(As + swz(wr + 16 + (lane & 15), fcb));
#pragma unroll
            for (int j = 0; j < NT; j++) {
                char* B = Bs + j * 8192;
                bf16x8 b0 = *(const bf16x8*)(B + swz(wc + (lane & 15), fcb));
                bf16x8 b1 = *(const bf16x8*)(B + swz(wc + 16 + (lane & 15), fcb));
                acc[j][0] = __builtin_amdgcn_mfma_f32_16x16x32_bf16(a0, b0, acc[j][0], 0, 0, 0);
                acc[j][1] = __builtin_amdgcn_mfma_f32_16x16x32_bf16(a0, b1, acc[j][1], 0, 0, 0);
                acc[j][2] = __builtin_amdgcn_mfma_f32_16x16x32_bf16(a1, b0, acc[j][2], 0, 0, 0);
                acc[j][3] = __builtin_amdgcn_mfma_f32_16x16x32_bf16(a1, b1, acc[j][3], 0, 0, 0);
            }
        }
    }
    // ---- cross-k-group reduce ----
    __syncthreads();
    float* red = (float*)sm;
    const int slot = (wi * 64 + lane) * 16;
    if (kg == 1) {
#pragma unroll
        for (int j = 0; j < NT; j++)
#pragma unroll
            for (int q = 0; q < 4; q++)
#pragma unroll
                for (int r = 0; r < 4; r++)
                    red[j * 4096 + slot + q * 4 + r] = acc[j][q][r];
    }
    __syncthreads();
    if (kg == 0) {
        const int er = (lane >> 4) * 4, ec = lane & 15;
#pragma unroll
        for (int q = 0; q < 4; q++) {
            int rr = m0 + wr + (q >> 1) * 16 + er;
            int cc = n0 + wc + (q & 1) * 16 + ec;
#pragma unroll
            for (int r = 0; r < 4; r++) {
                float vals[NT];
#pragma unroll
                for (int j = 0; j < NT; j++)
                    vals[j] = acc[j][q][r] + red[j * 4096 + slot + q * 4 + r];
                fe(rr + r, cc, vals);
            }
        }
    }
}

// -------- prolog: all weight prep + init (proven R4 pattern, 320-pad) --------
#define PREP_BLOCKS 2048
#define PGSTR (PREP_BLOCKS * 256)
__device__ __forceinline__ void tpose(const float* __restrict__ in, u16* __restrict__ out,
                                      int R, int C, int Rpad, int total, int gtid) {
    for (int i = gtid; i < total; i += PGSTR) {
        int r = i % Rpad;
        int bc = i / Rpad;
        int c = bc % C;
        int bb = bc / C;
        out[i] = (r < R) ? f2bf(in[((size_t)bb * R + r) * C + c]) : (u16)0;
    }
}
__device__ __forceinline__ void castb(const float* __restrict__ in, u16* __restrict__ out,
                                      int total, int gtid) {
    for (int i = gtid; i < total; i += PGSTR) out[i] = f2bf(in[i]);
}

__global__ void __launch_bounds__(256) k_prep(
    const float* W_embed, const float* W_ih, const float* W_hh, const float* W_ens,
    const float* Wp1, const float* Wp2, const float* Wq1, const float* Wq2,
    u16* Wembed_t, u16* Wih_b, u16* Whh_b, u16* Wens_t,
    u16* Wp1_t, u16* Wp2_t, u16* Wq1d_t, u16* Wq1o_t, u16* Wq2_t,
    const float* init_deter, const float* init_stoch, const float* action,
    const float* nonterms, float* deter, u16* h_nt, u16* x_embed) {
    int gtid = blockIdx.x * 256 + threadIdx.x;
    tpose(W_embed, Wembed_t, 288, 1024, 320, 1024 * 320, gtid);
    castb(W_ih, Wih_b, 3072 * 1024, gtid);
    castb(W_hh, Whh_b, 3072 * 1024, gtid);
    tpose(W_ens, Wens_t, 1024, 256, 1024, 5 * 256 * 1024, gtid);
    tpose(Wp1, Wp1_t, 1024, 1024, 1024, 1024 * 1024, gtid);
    tpose(Wp2, Wp2_t, 1024, 512, 1024, 512 * 1024, gtid);
    tpose(Wq1, Wq1d_t, 1024, 1024, 1024, 1024 * 1024, gtid);
    tpose(Wq1 + 1024 * 1024, Wq1o_t, 1024, 1024, 1024, 1024 * 1024, gtid);
    tpose(Wq2, Wq2_t, 1024, 512, 1024, 512 * 1024, gtid);
    for (int idx = gtid; idx < 262144; idx += PGSTR) {
        int b = idx >> 10, d = idx & 1023;
        float nt0 = nonterms[b * 64];
        float dv = init_deter[idx];
        deter[idx] = dv;
        h_nt[idx] = f2bf(dv * nt0);
        if (d < 256) {
            x_embed[b * 320 + d] = f2bf(init_stoch[b * 256 + d] * nt0);
        } else if (d < 320) {
            int c = d - 256;
            x_embed[b * 320 + d] = (c < 32) ? f2bf(action[(size_t)b * 2048 + c] * nt0) : (u16)0;
        }
    }
}

// -------- OBSC precompute (1008 blocks, proven R3 path) --------
__global__ void __launch_bounds__(256) k_obsc(const float* __restrict__ obs,
                                              const u16* __restrict__ Wq1o_t,
                                              u16* __restrict__ OBSC) {
    __shared__ char sm[40960];
    int bid = blockIdx.x;
    int rb = bid >> 2, cg = bid & 3;
    int m0 = rb * 64, n0 = cg * 256;
    auto fa = [&](int r, int k) {
        int tt = r >> 8, bb = r & 255;
        const float* p = obs + ((size_t)bb * 64 + tt) * 1024 + k;
        float4 f0 = *(const float4*)p, f1 = *(const float4*)(p + 4);
        union { u16 h[8]; uint4 q; } x;
        x.h[0] = f2bf(f0.x); x.h[1] = f2bf(f0.y); x.h[2] = f2bf(f0.z); x.h[3] = f2bf(f0.w);
        x.h[4] = f2bf(f1.x); x.h[5] = f2bf(f1.y); x.h[6] = f2bf(f1.z); x.h[7] = f2bf(f1.w);
        return x.q;
    };
    auto fe = [&](int r, int n, const float* v) {
#pragma unroll
        for (int j = 0; j < 4; j++) OBSC[(size_t)r * 1024 + n + j * 64] = f2bf(v[j]);
    };
    gemmN<4>(sm, fa, Wq1o_t, 1024, n0, 64, 1024, m0, fe);
}

// -------- S1: sa (64 blocks × 256thr, K=320) --------
__global__ void __launch_bounds__(256) k_sa(const u16* __restrict__ xe,
                                            const u16* __restrict__ Wt,
                                            const float* __restrict__ bias,
                                            u16* __restrict__ sa) {
    __shared__ char sm[16384];
    int m0 = blockIdx.y * 64, n0 = blockIdx.x * 64;
    auto fa = [&](int r, int k) { return *(const uint4*)(xe + r * 320 + k); };
    auto fe = [&](int r, int n, const float* v) {
        sa[r * 1024 + n] = f2bf(eluf(v[0] + bias[n]));
    };
    gemmN<1>(sm, fa, Wt, 320, n0, 0, 320, m0, fe);
}

// -------- S2: gi (192) || gh (192) — 384 blocks × 512thr split-K --------
__global__ void __launch_bounds__(512) k_gigh(const u16* __restrict__ sa,
                                              const u16* __restrict__ h_nt,
                                              const u16* __restrict__ Wih_b,
                                              const u16* __restrict__ Whh_b,
                                              const float* __restrict__ b_ih,
                                              const float* __restrict__ b_hh,
                                              float* __restrict__ gi,
                                              float* __restrict__ gh) {
    __shared__ char sm[32768];
    int bid = blockIdx.x;
    bool isgh = bid >= 192;
    int j = isgh ? bid - 192 : bid;
    int m0 = (j / 48) * 64, n0 = (j % 48) * 64;
    const u16* A = isgh ? h_nt : sa;
    const u16* B = isgh ? Whh_b : Wih_b;
    const float* bi = isgh ? b_hh : b_ih;
    float* dst = isgh ? gh : gi;
    auto fa = [&](int r, int k) { return *(const uint4*)(A + r * 1024 + k); };
    auto fe = [&](int r, int n, const float* v) { dst[(size_t)r * 3072 + n] = v[0] + bi[n]; };
    gemmS<1>(sm, fa, B, 1024, n0, 0, 1024, m0, fe);
}

// -------- S3: GRU elementwise (1024 blocks × 256, proven R3) --------
__global__ void __launch_bounds__(256) k_gru(const float* __restrict__ gi,
                                             const float* __restrict__ gh,
                                             float* __restrict__ deter,
                                             const float* __restrict__ nonterms, int t,
                                             u16* __restrict__ deter_b,
                                             u16* __restrict__ h_nt,
                                             float* __restrict__ out) {
    int idx = blockIdx.x * 256 + threadIdx.x;
    int b = idx >> 10, d = idx & 1023;
    float nt = nonterms[b * 64 + t];
    float h = deter[idx] * nt;
    size_t gb = (size_t)b * 3072;
    float r = sigm(gi[gb + d] + gh[gb + d]);
    float z = sigm(gi[gb + 1024 + d] + gh[gb + 1024 + d]);
    float n = tanhfast(gi[gb + 2048 + d] + r * gh[gb + 2048 + d]);
    float dn = (1.f - z) * n + z * h;
    deter[idx] = dn;
    deter_b[idx] = f2bf(dn);
    h_nt[idx] = f2bf(dn * nonterms[b * 64 + t + 1]);
    float* ob = out + (size_t)b * OUTT + (size_t)t * OUTC;
    ob[768 + d] = dn;
    ob[2560 + d] = dn;
}

// -------- S4: hp (64) || hq+OBSC (64) || ens→out (80) — 208 blocks × 512thr --------
__global__ void __launch_bounds__(512) k_hpqe(const u16* __restrict__ deter_b,
                                              const u16* __restrict__ sa,
                                              const u16* __restrict__ Wp1_t,
                                              const u16* __restrict__ Wq1d_t,
                                              const u16* __restrict__ Wens_t,
                                              const float* __restrict__ bp1,
                                              const float* __restrict__ bq1,
                                              const float* __restrict__ b_ens,
                                              const u16* __restrict__ OBSC,
                                              u16* __restrict__ HP,
                                              u16* __restrict__ HQ,
                                              float* __restrict__ out, int t) {
    __shared__ char sm[32768];
    int bid = blockIdx.x;
    if (bid < 128) {
        bool isq = bid >= 64;
        int j = bid & 63;
        int m0 = (j >> 4) * 64, n0 = (j & 15) * 64;
        const u16* B = isq ? Wq1d_t : Wp1_t;
        const float* bi = isq ? bq1 : bp1;
        u16* dst = isq ? HQ : HP;
        const u16* ob = OBSC + (size_t)t * 262144;
        auto fa = [&](int r, int k) { return *(const uint4*)(deter_b + r * 1024 + k); };
        auto fe = [&](int r, int n, const float* v) {
            float x = v[0] + bi[n];
            if (isq) x += bf2f(ob[r * 1024 + n]);
            dst[r * 1024 + n] = f2bf(eluf(x));
        };
        gemmS<1>(sm, fa, B, 1024, n0, 0, 1024, m0, fe);
    } else {
        int j = bid - 128;
        int m0 = (j / 20) * 64, n0 = (j % 20) * 64;
        float* op = out + (size_t)t * OUTC + 3584;
        auto fa = [&](int r, int k) { return *(const uint4*)(sa + r * 1024 + k); };
        auto fe = [&](int r, int n, const float* v) {
            op[(size_t)r * OUTT + n] = v[0] + b_ens[n];
        };
        gemmS<1>(sm, fa, Wens_t, 1024, n0, 0, 1024, m0, fe);
    }
}

// -------- S5: p2+prior || q2+post+x_embed || action-writer — 36 blocks × 512thr --------
__global__ void __launch_bounds__(512) k_pqdist(const u16* __restrict__ HP,
                                                const u16* __restrict__ HQ,
                                                const u16* __restrict__ Wp2_t,
                                                const u16* __restrict__ Wq2_t,
                                                const float* __restrict__ bp2,
                                                const float* __restrict__ bq2,
                                                const float* __restrict__ noise_p,
                                                const float* __restrict__ noise_q,
                                                const float* __restrict__ nonterms,
                                                const float* __restrict__ action,
                                                float* __restrict__ out,
                                                u16* __restrict__ x_embed, int t) {
    __shared__ char sm[49152];
    int bid = blockIdx.x;
    if (bid < 32) {
        bool isq = bid >= 16;
        int j = bid & 15;
        int m0 = (j >> 2) * 64, n0 = (j & 3) * 64;
        const u16* A = isq ? HQ : HP;
        const u16* B = isq ? Wq2_t : Wp2_t;
        const float* b2 = isq ? bq2 : bp2;
        const float* noise = isq ? noise_q : noise_p;
        int obase = isq ? 1792 : 0;
        auto fa = [&](int r, int k) { return *(const uint4*)(A + r * 1024 + k); };
        auto fe = [&](int r, int s, const float* v) {
            float m = v[0] + b2[s];
            float sd = splus(v[1] + b2[s + 256]) + 0.1f;
            float eps = noise[(size_t)t * 65536 + r * 256 + s];
            float st = m + sd * eps;
            float* obp = out + (size_t)r * OUTT + (size_t)t * OUTC + obase;
            obp[s] = m;
            obp[256 + s] = sd;
            obp[512 + s] = st;
            if (isq) {
                float ntn = nonterms[r * 64 + t + 1];
                x_embed[r * 320 + s] = f2bf(st * ntn);
            }
        };
        gemmS<2>(sm, fa, B, 1024, n0, 256, 1024, m0, fe);
    } else {
        for (int i = (bid - 32) * 512 + threadIdx.x; i < 8192; i += 2048) {
            int b = i >> 5, c = i & 31;
            float ntn = nonterms[b * 64 + t + 1];
            x_embed[b * 320 + 256 + c] =
                f2bf(action[(size_t)b * 2048 + (size_t)(t + 1) * 32 + c] * ntn);
        }
    }
}

// ---------------- host ----------------
extern "C" void kernel_launch(void* const* d_in, const int* in_sizes, int n_in,
                              void* d_out, int out_size, void* d_ws, size_t ws_size,
                              hipStream_t stream) {
    const float* obs = (const float*)d_in[1];
    const float* action = (const float*)d_in[2];
    const float* nonterms = (const float*)d_in[3];
    const float* init_deter = (const float*)d_in[4];
    const float* init_stoch = (const float*)d_in[5];
    const float* noise_p = (const float*)d_in[6];
    const float* noise_q = (const float*)d_in[7];
    const float* W_embed = (const float*)d_in[8];
    const float* b_embed = (const float*)d_in[9];
    const float* W_ens = (const float*)d_in[10];
    const float* b_ens = (const float*)d_in[11];
    const float* W_ih = (const float*)d_in[12];
    const float* W_hh = (const float*)d_in[13];
    const float* b_ih = (const float*)d_in[14];
    const float* b_hh = (const float*)d_in[15];
    const float* Wp1 = (const float*)d_in[16];
    const float* bp1 = (const float*)d_in[17];
    const float* Wp2 = (const float*)d_in[18];
    const float* bp2 = (const float*)d_in[19];
    const float* Wq1 = (const float*)d_in[20];
    const float* bq1 = (const float*)d_in[21];
    const float* Wq2 = (const float*)d_in[22];
    const float* bq2 = (const float*)d_in[23];
    float* out = (float*)d_out;

    char* ws = (char*)d_ws;
    size_t off = 0;
    auto alloc = [&](size_t bytes) {
        void* p = ws + off;
        off += (bytes + 255) & ~(size_t)255;
        return p;
    };
    u16* Wembed_t = (u16*)alloc((size_t)1024 * 320 * 2);
    u16* Wih_b = (u16*)alloc((size_t)3072 * 1024 * 2);
    u16* Whh_b = (u16*)alloc((size_t)3072 * 1024 * 2);
    u16* Wens_t = (u16*)alloc((size_t)1280 * 1024 * 2);
    u16* Wp1_t = (u16*)alloc((size_t)1024 * 1024 * 2);
    u16* Wp2_t = (u16*)alloc((size_t)512 * 1024 * 2);
    u16* Wq1d_t = (u16*)alloc((size_t)1024 * 1024 * 2);
    u16* Wq1o_t = (u16*)alloc((size_t)1024 * 1024 * 2);
    u16* Wq2_t = (u16*)alloc((size_t)512 * 1024 * 2);
    u16* OBSC = (u16*)alloc((size_t)16128 * 1024 * 2);
    u16* x_embed = (u16*)alloc((size_t)256 * 320 * 2);
    u16* h_nt = (u16*)alloc((size_t)256 * 1024 * 2);
    u16* sa = (u16*)alloc((size_t)256 * 1024 * 2);
    u16* deter_b = (u16*)alloc((size_t)256 * 1024 * 2);
    u16* HP = (u16*)alloc((size_t)256 * 1024 * 2);
    u16* HQ = (u16*)alloc((size_t)256 * 1024 * 2);
    float* deter = (float*)alloc((size_t)256 * 1024 * 4);
    float* gi = (float*)alloc((size_t)256 * 3072 * 4);
    float* gh = (float*)alloc((size_t)256 * 3072 * 4);
    (void)ws_size; (void)in_sizes; (void)n_in; (void)out_size;

    k_prep<<<PREP_BLOCKS, 256, 0, stream>>>(
        W_embed, W_ih, W_hh, W_ens, Wp1, Wp2, Wq1, Wq2,
        Wembed_t, Wih_b, Whh_b, Wens_t, Wp1_t, Wp2_t, Wq1d_t, Wq1o_t, Wq2_t,
        init_deter, init_stoch, action, nonterms, deter, h_nt, x_embed);
    k_obsc<<<1008, 256, 0, stream>>>(obs, Wq1o_t, OBSC);

    for (int t = 0; t < 63; t++) {
        k_sa<<<dim3(16, 4), 256, 0, stream>>>(x_embed, Wembed_t, b_embed, sa);
        k_gigh<<<384, 512, 0, stream>>>(sa, h_nt, Wih_b, Whh_b, b_ih, b_hh, gi, gh);
        k_gru<<<1024, 256, 0, stream>>>(gi, gh, deter, nonterms, t, deter_b, h_nt, out);
        k_hpqe<<<208, 512, 0, stream>>>(deter_b, sa, Wp1_t, Wq1d_t, Wens_t,
                                        bp1, bq1, b_ens, OBSC, HP, HQ, out, t);
        k_pqdist<<<36, 512, 0, stream>>>(HP, HQ, Wp2_t, Wq2_t, bp2, bq2,
                                         noise_p, noise_q, nonterms, action,
                                         out, x_embed, t);
    }
}